// Round 1
// baseline (43003.961 us; speedup 1.0000x reference)
//
#include <hip/hip_runtime.h>

#define B_ 32
#define T_ 512
#define H_ 1024
#define TOK_ 26
#define EMB_ 512
#define OUT_ 26

// ---------------- kernel 1: fuse embed weights ----------------
// Wt[h][k] = sum_e W_emb[h][e]     * W_tok[e][k]    (e<256, k<26)
// Wc[h][k] = sum_e W_emb[h][256+e] * W_coord[e][k]
__global__ void k_fuse_w(const float* __restrict__ W_emb, const float* __restrict__ W_tok,
                         const float* __restrict__ W_coord, float* __restrict__ Wt,
                         float* __restrict__ Wc) {
    int idx = blockIdx.x * 256 + threadIdx.x;
    if (idx >= 2 * H_ * TOK_) return;
    int which = idx >= H_ * TOK_;
    int rem = idx - which * (H_ * TOK_);
    int h = rem / TOK_;
    int k = rem - h * TOK_;
    const float* Wsel = which ? W_coord : W_tok;
    const float* we = W_emb + (size_t)h * EMB_ + which * 256;
    float acc = 0.f;
#pragma unroll 8
    for (int e = 0; e < 256; ++e) acc += we[e] * Wsel[e * TOK_ + k];
    (which ? Wc : Wt)[h * TOK_ + k] = acc;
}

// ---------------- kernel 2: fused embed ----------------
// emb[row][h] = relu(b_emb[h] + sum_k t[row][k]*Wt[h][k] + c[row][k]*Wc[h][k])
__global__ void k_embed(const float* __restrict__ t_in, const float* __restrict__ c_in,
                        const float* __restrict__ Wt, const float* __restrict__ Wc,
                        const float* __restrict__ b_emb, float* __restrict__ emb) {
    int row = blockIdx.x;  // b*T_ + t
    int tid = threadIdx.x;
    __shared__ float tv[TOK_], cv[TOK_];
    if (tid < TOK_) tv[tid] = t_in[(size_t)row * TOK_ + tid];
    else if (tid < 2 * TOK_) cv[tid - TOK_] = c_in[(size_t)row * TOK_ + (tid - TOK_)];
    __syncthreads();
#pragma unroll
    for (int i = 0; i < 4; ++i) {
        int h = tid + i * 256;
        float acc = b_emb[h];
        const float* wt = Wt + h * TOK_;
        const float* wc = Wc + h * TOK_;
#pragma unroll
        for (int k = 0; k < TOK_; ++k) acc += tv[k] * wt[k] + cv[k] * wc[k];
        emb[(size_t)row * H_ + h] = fmaxf(acc, 0.f);
    }
}

// ---------------- kernel 3: one GRU layer step ----------------
// grid = 256 WGs (4 dims each), block = 512:
//   b = tid&31, dd = (tid>>5)&3, ks = tid>>7 in {0:x-low,1:x-high,2:h-low,3:h-high}
__global__ __launch_bounds__(512) void k_gru(
    const float* __restrict__ x_base, long long x_stride,
    const float* __restrict__ h_prev, float* __restrict__ h_new,
    const float* __restrict__ W_ih, const float* __restrict__ W_hh,
    const float* __restrict__ b_ih, const float* __restrict__ b_hh,
    float* __restrict__ o_act, float* __restrict__ o_z,
    float* __restrict__ o_r, float* __restrict__ o_n, int t) {
    __shared__ float xt[32][132];   // cols 0..63 = low K window, 64..127 = high K window
    __shared__ float ht[32][132];
    __shared__ float part[3][4][32][3];
    int tid = threadIdx.x;
    int b = tid & 31;
    int dd = (tid >> 5) & 3;
    int ks = tid >> 7;
    int d = blockIdx.x * 4 + dd;
    int mat = ks >> 1;    // 0 = x side (W_ih), 1 = h side (W_hh)
    int khalf = ks & 1;   // which 512-wide K half
    const float* Wb = mat ? W_hh : W_ih;
    const float* Wr = Wb + (size_t)d * H_;
    const float* Wz = Wb + (size_t)(H_ + d) * H_;
    const float* Wn = Wb + (size_t)(2 * H_ + d) * H_;
    float ar = 0.f, az = 0.f, an = 0.f;
    int cbase = khalf * 64;
    for (int it = 0; it < 8; ++it) {
        // cooperative stage: both tiles, both 64-wide windows (low: it*64.., high: 512+it*64..)
#pragma unroll
        for (int j = 0; j < 4; ++j) {
            int i4 = tid + j * 512;       // [0,2048) float4 slots
            int sel = i4 >> 10;           // 0 -> xt, 1 -> ht
            int slot = i4 & 1023;
            int bb = slot >> 5;           // 32 float4 per row
            int cc = (slot & 31) << 2;
            int gc = (cc < 64) ? (it * 64 + cc) : (512 + it * 64 + (cc - 64));
            const float* src = sel ? (h_prev + (size_t)bb * H_)
                                   : (x_base + (size_t)bb * x_stride);
            float4 v = *(const float4*)(src + gc);
            float* dst = sel ? &ht[bb][cc] : &xt[bb][cc];
            *(float4*)dst = v;
        }
        __syncthreads();
        const float(*tile)[132] = mat ? ht : xt;
        int koff = khalf * 512 + it * 64;
#pragma unroll
        for (int k = 0; k < 64; k += 4) {
            float4 v = *(const float4*)&tile[b][cbase + k];
            float4 wr = *(const float4*)(Wr + koff + k);
            float4 wz = *(const float4*)(Wz + koff + k);
            float4 wn = *(const float4*)(Wn + koff + k);
            ar += v.x * wr.x + v.y * wr.y + v.z * wr.z + v.w * wr.w;
            az += v.x * wz.x + v.y * wz.y + v.z * wz.z + v.w * wz.w;
            an += v.x * wn.x + v.y * wn.y + v.z * wn.z + v.w * wn.w;
        }
        __syncthreads();
    }
    if (ks != 0) {
        part[ks - 1][dd][b][0] = ar;
        part[ks - 1][dd][b][1] = az;
        part[ks - 1][dd][b][2] = an;
    }
    __syncthreads();
    if (ks == 0) {
        float rpre = ar + part[0][dd][b][0] + part[1][dd][b][0] + part[2][dd][b][0]
                   + b_ih[d] + b_hh[d];
        float zpre = az + part[0][dd][b][1] + part[1][dd][b][1] + part[2][dd][b][1]
                   + b_ih[H_ + d] + b_hh[H_ + d];
        float ni = an + part[0][dd][b][2] + b_ih[2 * H_ + d];                 // x-side n
        float nh = part[1][dd][b][2] + part[2][dd][b][2] + b_hh[2 * H_ + d]; // h-side n
        float r = 1.f / (1.f + expf(-rpre));
        float z = 1.f / (1.f + expf(-zpre));
        float n = tanhf(ni + r * nh);
        float hp = h_prev[b * H_ + d];
        float hn = n + z * (hp - n);
        h_new[b * H_ + d] = hn;
        size_t o = ((size_t)b * T_ + t) * H_ + d;
        o_act[o] = hn;
        o_z[o] = z;
        o_r[o] = r;
        o_n[o] = n;
    }
}

// ---------------- kernel 4: LayerNorm row stats ----------------
__global__ void k_lnstats(const float* __restrict__ top, float* __restrict__ stats) {
    int row = blockIdx.x;
    int tid = threadIdx.x;
    float4 v = *(const float4*)(top + (size_t)row * H_ + tid * 4);
    float s = v.x + v.y + v.z + v.w;
    float ss = v.x * v.x + v.y * v.y + v.z * v.z + v.w * v.w;
    for (int off = 32; off; off >>= 1) {
        s += __shfl_down(s, off, 64);
        ss += __shfl_down(ss, off, 64);
    }
    __shared__ float sb[4], ssb[4];
    int w = tid >> 6;
    if ((tid & 63) == 0) { sb[w] = s; ssb[w] = ss; }
    __syncthreads();
    if (tid == 0) {
        float S = sb[0] + sb[1] + sb[2] + sb[3];
        float SS = ssb[0] + ssb[1] + ssb[2] + ssb[3];
        float mu = S * (1.f / H_);
        float var = SS * (1.f / H_) - mu * mu;
        stats[row * 2] = mu;
        stats[row * 2 + 1] = rsqrtf(var + 1e-5f);
    }
}

// ---------------- kernel 5: fc = relu(LN(top) @ W_fc.T), LN fused into staging ----------------
__global__ __launch_bounds__(256) void k_fc(const float* __restrict__ top,
                                            const float* __restrict__ stats,
                                            const float* __restrict__ gamma,
                                            const float* __restrict__ beta,
                                            const float* __restrict__ W_fc,
                                            float* __restrict__ fc_out) {
    __shared__ float At[64][17];
    __shared__ float Bt[64][17];
    __shared__ float mu_s[64], rs_s[64];
    int tid = threadIdx.x;
    int m0 = blockIdx.x * 64;
    int j0 = blockIdx.y * 64;
    if (tid < 64) {
        mu_s[tid] = stats[(size_t)(m0 + tid) * 2];
        rs_s[tid] = stats[(size_t)(m0 + tid) * 2 + 1];
    }
    __syncthreads();
    int ty = tid >> 4, tx = tid & 15;
    float acc[4][4] = {};
    for (int kt = 0; kt < H_; kt += 16) {
#pragma unroll
        for (int i = 0; i < 4; ++i) {
            int idx = tid + i * 256;
            int r = idx >> 4, k = idx & 15;
            float raw = top[(size_t)(m0 + r) * H_ + kt + k];
            At[r][k] = (raw - mu_s[r]) * rs_s[r] * gamma[kt + k] + beta[kt + k];
            Bt[r][k] = W_fc[(size_t)(j0 + r) * H_ + kt + k];
        }
        __syncthreads();
#pragma unroll
        for (int k = 0; k < 16; ++k) {
            float a0 = At[ty * 4 + 0][k], a1 = At[ty * 4 + 1][k];
            float a2 = At[ty * 4 + 2][k], a3 = At[ty * 4 + 3][k];
            float b0 = Bt[tx * 4 + 0][k], b1 = Bt[tx * 4 + 1][k];
            float b2 = Bt[tx * 4 + 2][k], b3 = Bt[tx * 4 + 3][k];
            acc[0][0] += a0 * b0; acc[0][1] += a0 * b1; acc[0][2] += a0 * b2; acc[0][3] += a0 * b3;
            acc[1][0] += a1 * b0; acc[1][1] += a1 * b1; acc[1][2] += a1 * b2; acc[1][3] += a1 * b3;
            acc[2][0] += a2 * b0; acc[2][1] += a2 * b1; acc[2][2] += a2 * b2; acc[2][3] += a2 * b3;
            acc[3][0] += a3 * b0; acc[3][1] += a3 * b1; acc[3][2] += a3 * b2; acc[3][3] += a3 * b3;
        }
        __syncthreads();
    }
#pragma unroll
    for (int i = 0; i < 4; ++i)
#pragma unroll
        for (int j = 0; j < 4; ++j)
            fc_out[(size_t)(m0 + ty * 4 + i) * H_ + j0 + tx * 4 + j] = fmaxf(acc[i][j], 0.f);
}

// ---------------- kernel 6: readout out = fc_out @ W_ro.T ----------------
__global__ void k_ro(const float* __restrict__ fc_out, const float* __restrict__ W_ro,
                     float* __restrict__ out) {
    int row = blockIdx.x;
    int tid = threadIdx.x;
    __shared__ float xrow[H_];
    *(float4*)&xrow[tid * 4] = *(const float4*)(fc_out + (size_t)row * H_ + tid * 4);
    __syncthreads();
    int o = tid >> 3, ks = tid & 7;  // 8 K-slices of 128
    float acc = 0.f;
    if (o < OUT_) {
        const float* w = W_ro + (size_t)o * H_ + ks * 128;
        const float* xs = xrow + ks * 128;
#pragma unroll 16
        for (int k = 0; k < 128; ++k) {
            int idx = (k + 4 * ks) & 127;  // bank-swizzled walk
            acc += xs[idx] * w[idx];
        }
    }
    __shared__ float red[OUT_][8];
    if (o < OUT_) red[o][ks] = acc;
    __syncthreads();
    if (tid < OUT_) {
        float s = 0.f;
#pragma unroll
        for (int i = 0; i < 8; ++i) s += red[tid][i];
        out[(size_t)row * OUT_ + tid] = s;
    }
}

extern "C" void kernel_launch(void* const* d_in, const int* in_sizes, int n_in,
                              void* d_out, int out_size, void* d_ws, size_t ws_size,
                              hipStream_t stream) {
    (void)in_sizes; (void)n_in; (void)out_size; (void)ws_size;
    const float* t_in    = (const float*)d_in[0];
    const float* c_in    = (const float*)d_in[1];
    const float* W_tok   = (const float*)d_in[2];
    const float* W_coord = (const float*)d_in[3];
    const float* W_emb   = (const float*)d_in[4];
    const float* b_emb   = (const float*)d_in[5];
    const float* W_ih    = (const float*)d_in[6];
    const float* W_hh    = (const float*)d_in[7];
    const float* b_ih    = (const float*)d_in[8];
    const float* b_hh    = (const float*)d_in[9];
    const float* gamma   = (const float*)d_in[10];
    const float* beta    = (const float*)d_in[11];
    const float* W_fc    = (const float*)d_in[12];
    const float* W_ro    = (const float*)d_in[13];

    float* out = (float*)d_out;
    const size_t NOUT0 = (size_t)B_ * T_ * OUT_;       // 425984
    const size_t NBTH  = (size_t)B_ * T_ * H_;         // 16777216
    const size_t NLBTH = 2 * NBTH;                     // 33554432
    float* o_acts = out + NOUT0;
    float* o_z = o_acts + NLBTH;
    float* o_r = o_z + NLBTH;
    float* o_n = o_r + NLBTH;

    float* ws = (float*)d_ws;
    float* fc_out = ws;                    // 16777216 floats (64 MB)
    float* stats  = ws + 16777216;         // 32768 floats
    float* hbuf   = stats + 32768;         // 4 * 32768 floats: h[parity][layer]
    float* Wt     = hbuf + 4 * B_ * H_;    // 26624 floats
    float* Wc     = Wt + H_ * TOK_;        // 26624 floats

    // emb overlays the ng layer-1 output region: emb rows (.,t) are consumed by the
    // layer-0 kernel of step t strictly before the layer-1 kernel of step t writes
    // ng[l=1] rows (.,t); ng rows written so far never collide with emb rows still needed.
    float* emb = o_n + NBTH;

    // zero initial hidden state (parity 0, both layers)
    hipMemsetAsync(hbuf, 0, (size_t)2 * B_ * H_ * sizeof(float), stream);

    k_fuse_w<<<(2 * H_ * TOK_ + 255) / 256, 256, 0, stream>>>(W_emb, W_tok, W_coord, Wt, Wc);
    k_embed<<<B_ * T_, 256, 0, stream>>>(t_in, c_in, Wt, Wc, b_emb, emb);

    for (int t = 0; t < T_; ++t) {
        int rp = t & 1, wp = rp ^ 1;
        float* h0r = hbuf + (rp * 2 + 0) * (B_ * H_);
        float* h0w = hbuf + (wp * 2 + 0) * (B_ * H_);
        float* h1r = hbuf + (rp * 2 + 1) * (B_ * H_);
        float* h1w = hbuf + (wp * 2 + 1) * (B_ * H_);
        k_gru<<<256, 512, 0, stream>>>(emb + (size_t)t * H_, (long long)(T_ * H_),
                                       h0r, h0w, W_ih, W_hh, b_ih, b_hh,
                                       o_acts, o_z, o_r, o_n, t);
        k_gru<<<256, 512, 0, stream>>>(h0w, (long long)H_,
                                       h1r, h1w,
                                       W_ih + (size_t)3 * H_ * H_, W_hh + (size_t)3 * H_ * H_,
                                       b_ih + 3 * H_, b_hh + 3 * H_,
                                       o_acts + NBTH, o_z + NBTH, o_r + NBTH, o_n + NBTH, t);
    }

    k_lnstats<<<B_ * T_, 256, 0, stream>>>(o_acts + NBTH, stats);
    k_fc<<<dim3((B_ * T_) / 64, H_ / 64), 256, 0, stream>>>(o_acts + NBTH, stats, gamma, beta,
                                                            W_fc, fc_out);
    k_ro<<<B_ * T_, 256, 0, stream>>>(fc_out, W_ro, out);
}